// Round 1
// baseline (5427.061 us; speedup 1.0000x reference)
//
#include <hip/hip_runtime.h>

#define DIMD 256
#define SEQT 1024
#define NB   4

__device__ __forceinline__ float sigmoidf_(float x){ return 1.0f/(1.0f+expf(-x)); }

// ---------------------------------------------------------------------------
// GEMM: C[m][n] = sum_k A[m][k] * B[n][k], K = 256 fixed, tiles 64x64.
// EPI==1: C *= sigmoid(gpre[m*N+n])
// grid.x = (M/64)*(N/64)
// ---------------------------------------------------------------------------
template<int EPI>
__global__ __launch_bounds__(256) void gemm_bt(const float* __restrict__ A,
    const float* __restrict__ Bm, float* __restrict__ C, int N,
    const float* __restrict__ gpre)
{
  __shared__ float sA[64][68];
  __shared__ float sB[64][68];
  const int nb = N >> 6;
  const int bm = blockIdx.x / nb, bn = blockIdx.x - bm*nb;
  const int m0 = bm << 6, n0 = bn << 6;
  const int tid = threadIdx.x;
  const int tr = tid >> 4, tc = tid & 15;
  float acc[4][4];
  #pragma unroll
  for (int i=0;i<4;i++)
    #pragma unroll
    for (int j=0;j<4;j++) acc[i][j]=0.f;

  for (int kc=0;kc<4;kc++){
    __syncthreads();
    for (int i=tid;i<1024;i+=256){
      int r = i >> 4, q4 = i & 15;
      *(float4*)&sA[r][q4*4] = ((const float4*)(A  + (m0+r)*256 + kc*64))[q4];
      *(float4*)&sB[r][q4*4] = ((const float4*)(Bm + (n0+r)*256 + kc*64))[q4];
    }
    __syncthreads();
    #pragma unroll
    for (int kq=0;kq<16;kq++){
      float4 av[4], bv[4];
      #pragma unroll
      for (int i=0;i<4;i++) av[i] = *(const float4*)&sA[tr+16*i][kq*4];
      #pragma unroll
      for (int j=0;j<4;j++) bv[j] = *(const float4*)&sB[tc+16*j][kq*4];
      #pragma unroll
      for (int i=0;i<4;i++)
        #pragma unroll
        for (int j=0;j<4;j++)
          acc[i][j] = fmaf(av[i].x,bv[j].x, fmaf(av[i].y,bv[j].y,
                      fmaf(av[i].z,bv[j].z, fmaf(av[i].w,bv[j].w, acc[i][j]))));
    }
  }
  #pragma unroll
  for (int i=0;i<4;i++){
    #pragma unroll
    for (int j=0;j<4;j++){
      int m = m0 + tr + 16*i, n = n0 + tc + 16*j;
      float val = acc[i][j];
      if (EPI==1) val *= sigmoidf_(gpre[m*N+n]);
      C[m*N+n] = val;
    }
  }
}

// ---------------------------------------------------------------------------
// prep: causal dwconv(4) + RoPE + l2norm for q,k ; conv for v ; eta/alpha.
// one block per (b,t), 256 threads (one per d)
// ---------------------------------------------------------------------------
__global__ __launch_bounds__(256) void prep_kernel(
    const float* __restrict__ qkvr, const float* __restrict__ x,
    const float* __restrict__ cosT, const float* __restrict__ sinT,
    const float* __restrict__ qw, const float* __restrict__ qbias,
    const float* __restrict__ kw, const float* __restrict__ kbias,
    const float* __restrict__ vw, const float* __restrict__ vbias,
    const float* __restrict__ Wparam, const float* __restrict__ bparam,
    float* __restrict__ qo, float* __restrict__ ko, float* __restrict__ vo,
    float* __restrict__ eo, float* __restrict__ ao)
{
  const int bt = blockIdx.x;
  const int t = bt & 1023;
  const int d = threadIdx.x;

  float4 wq = ((const float4*)qw)[d];
  float4 wk = ((const float4*)kw)[d];
  float4 wv = ((const float4*)vw)[d];
  const float wqj[4] = {wq.x,wq.y,wq.z,wq.w};
  const float wkj[4] = {wk.x,wk.y,wk.z,wk.w};
  const float wvj[4] = {wv.x,wv.y,wv.z,wv.w};
  float qa = qbias[d], ka = kbias[d], va = vbias[d];
  #pragma unroll
  for (int j=0;j<4;j++){
    int tt = t - 3 + j;
    if (tt >= 0) {
      const float* row = qkvr + (size_t)(bt - 3 + j) * 768;
      qa = fmaf(row[d],      wqj[j], qa);
      ka = fmaf(row[256+d],  wkj[j], ka);
      va = fmaf(row[512+d],  wvj[j], va);
    }
  }
  vo[bt*256 + d] = va;

  __shared__ float sq[256], sk[256];
  __shared__ float red[4][4];
  sq[d] = qa; sk[d] = ka;
  __syncthreads();
  const int i = d >> 1;
  const float c = cosT[t*128 + i], s = sinT[t*128 + i];
  float qr, krp;
  if ((d & 1) == 0) { qr = sq[d]*c - sq[d+1]*s;  krp = sk[d]*c - sk[d+1]*s; }
  else              { qr = sq[d-1]*s + sq[d]*c;  krp = sk[d-1]*s + sk[d]*c; }

  const float xd = x[bt*256 + d];
  float r0 = qr*qr, r1 = krp*krp, r2 = xd*Wparam[d], r3 = xd*Wparam[256+d];
  #pragma unroll
  for (int m=1;m<64;m<<=1){
    r0 += __shfl_xor(r0, m, 64);
    r1 += __shfl_xor(r1, m, 64);
    r2 += __shfl_xor(r2, m, 64);
    r3 += __shfl_xor(r3, m, 64);
  }
  const int w = d >> 6;
  if ((d & 63) == 0){ red[w][0]=r0; red[w][1]=r1; red[w][2]=r2; red[w][3]=r3; }
  __syncthreads();
  float qss = red[0][0]+red[1][0]+red[2][0]+red[3][0];
  float kss = red[0][1]+red[1][1]+red[2][1]+red[3][1];
  qo[bt*256+d] = qr  / fmaxf(sqrtf(qss), 1e-12f);
  ko[bt*256+d] = krp / fmaxf(sqrtf(kss), 1e-12f);
  if (d == 0){
    float p0 = red[0][2]+red[1][2]+red[2][2]+red[3][2] + bparam[0];
    float p1 = red[0][3]+red[1][3]+red[2][3]+red[3][3] + bparam[1];
    eo[bt] = 1.f/(1.f+expf(-p0));
    ao[bt] = 1.f/(1.f+expf(-p1));
  }
}

// ---------------------------------------------------------------------------
// scan: one block per batch, 512 threads. Thread (rg=tid>>7, ec=tid&127)
// owns A[rg*64 .. rg*64+63][{ec, ec+128}] in registers (128 VGPRs) and a
// 64-entry k cache. Two barriers per step; q/k/v/eta/alpha for t+1
// prefetched into a double-buffered LDS slot.
// ---------------------------------------------------------------------------
__global__ __launch_bounds__(512, 2) void scan_kernel(
    const float* __restrict__ qn, const float* __restrict__ kn,
    const float* __restrict__ vn, const float* __restrict__ eta,
    const float* __restrict__ alpha, const float* __restrict__ W0,
    float* __restrict__ y)
{
  const int b = blockIdx.x;
  const int tid = threadIdx.x;
  const int rg = tid >> 7;        // 0..3 row group
  const int ec = tid & 127;       // 0..127
  const int r0 = rg << 6;         // first owned row
  const int c0 = ec, c1 = ec + 128;

  __shared__ float s_k[2][256], s_q[2][256], s_v[2][256];
  __shared__ float s_ea[2][2];
  __shared__ float part[4][256], part2[4][256];
  __shared__ float s_s4[8];

  float A0[64], A1[64];
  #pragma unroll
  for (int j=0;j<64;j++){ A0[j]=0.f; A1[j]=0.f; }

  const float* kb = kn + b*SEQT*DIMD;
  const float* qb = qn + b*SEQT*DIMD;
  const float* vb = vn + b*SEQT*DIMD;
  const float* eb = eta   + b*SEQT;
  const float* ab = alpha + b*SEQT;
  float* yb = y + b*SEQT*DIMD;

  // stage t=0 into buffer 0
  if (tid < 64)        ((float4*)s_k[0])[tid]      = ((const float4*)kb)[tid];
  else if (tid < 128)  ((float4*)s_q[0])[tid-64]   = ((const float4*)qb)[tid-64];
  else if (tid < 192)  ((float4*)s_v[0])[tid-128]  = ((const float4*)vb)[tid-128];
  if (tid == 192) { s_ea[0][0] = eb[0]; s_ea[0][1] = ab[0]; }
  __syncthreads();

  float inv_prev = 1.0f;

  for (int t=0; t<SEQT; ++t) {
    const int cur = t & 1, nxt = cur ^ 1;

    // (a) issue prefetch of step t+1 (latency hidden under compute)
    float4 pf = make_float4(0.f,0.f,0.f,0.f);
    float pe = 0.f, pa = 0.f;
    if (t+1 < SEQT) {
      if (tid < 64)       pf = ((const float4*)(kb + (t+1)*DIMD))[tid];
      else if (tid < 128) pf = ((const float4*)(qb + (t+1)*DIMD))[tid-64];
      else if (tid < 192) pf = ((const float4*)(vb + (t+1)*DIMD))[tid-128];
      if (tid == 192) { pe = eb[t+1]; pa = ab[t+1]; }
    }

    // (b) k-dot: pred partials over owned rows (cache k in regs)
    float kr[64];
    float d0 = 0.f, d1 = 0.f;
    if (t == 0) {
      // W_{-1} = W0 (A is zero): pred = k . W0
      const float* w0p = W0 + r0*DIMD;
      #pragma unroll
      for (int j=0;j<64;j++){
        float kvv = s_k[cur][r0+j];
        kr[j] = kvv;
        d0 = fmaf(kvv, w0p[j*DIMD + c0], d0);
        d1 = fmaf(kvv, w0p[j*DIMD + c1], d1);
      }
    } else {
      const float4* kp = (const float4*)(s_k[cur] + r0);
      #pragma unroll
      for (int jq=0;jq<16;jq++){
        float4 kv4 = kp[jq];
        kr[4*jq+0]=kv4.x; kr[4*jq+1]=kv4.y; kr[4*jq+2]=kv4.z; kr[4*jq+3]=kv4.w;
        d0 = fmaf(kv4.x, A0[4*jq+0], d0); d0 = fmaf(kv4.y, A0[4*jq+1], d0);
        d0 = fmaf(kv4.z, A0[4*jq+2], d0); d0 = fmaf(kv4.w, A0[4*jq+3], d0);
        d1 = fmaf(kv4.x, A1[4*jq+0], d1); d1 = fmaf(kv4.y, A1[4*jq+1], d1);
        d1 = fmaf(kv4.z, A1[4*jq+2], d1); d1 = fmaf(kv4.w, A1[4*jq+3], d1);
      }
      d0 *= inv_prev; d1 *= inv_prev;   // fold W = A/denom
    }
    part[rg][c0] = d0; part[rg][c1] = d1;
    __syncthreads();                                   // B1

    // (d) pred -> g (redundant across the 4 row groups)
    float pr0 = part[0][c0]+part[1][c0]+part[2][c0]+part[3][c0];
    float pr1 = part[0][c1]+part[1][c1]+part[2][c1]+part[3][c1];
    const float et = s_ea[cur][0], al = s_ea[cur][1];
    float df0 = pr0 - s_v[cur][c0];
    float df1 = pr1 - s_v[cur][c1];
    // tanh(10*diff) = 1 - 2/(exp(20*diff)+1)   (saturates correctly at +-inf)
    float e0 = __expf(20.f*df0), e1 = __expf(20.f*df1);
    float th0 = 1.f - 2.f/(e0+1.f);
    float th1 = 1.f - 2.f/(e1+1.f);
    float g0 = 3.f * th0 * (df0*df0);
    float g1 = 3.f * th1 * (df1*df1);
    const float t0 = et*g0, t1 = et*g1;

    // (e) A update + sum A^4 partial
    float s4 = 0.f;
    #pragma unroll
    for (int j=0;j<64;j++){
      float a  = fmaf(al, A0[j], -t0*kr[j]);
      A0[j] = a;
      float a2 = a*a; s4 = fmaf(a2, a2, s4);
      float bb = fmaf(al, A1[j], -t1*kr[j]);
      A1[j] = bb;
      float b2 = bb*bb; s4 = fmaf(b2, b2, s4);
    }

    // (g) q-dot on the NEW A (scalar-free; scale after reduce)
    float u0 = 0.f, u1 = 0.f;
    {
      const float4* qp = (const float4*)(s_q[cur] + r0);
      #pragma unroll
      for (int jq=0;jq<16;jq++){
        float4 qv4 = qp[jq];
        u0 = fmaf(qv4.x, A0[4*jq+0], u0); u0 = fmaf(qv4.y, A0[4*jq+1], u0);
        u0 = fmaf(qv4.z, A0[4*jq+2], u0); u0 = fmaf(qv4.w, A0[4*jq+3], u0);
        u1 = fmaf(qv4.x, A1[4*jq+0], u1); u1 = fmaf(qv4.y, A1[4*jq+1], u1);
        u1 = fmaf(qv4.z, A1[4*jq+2], u1); u1 = fmaf(qv4.w, A1[4*jq+3], u1);
      }
    }
    part2[rg][c0] = u0; part2[rg][c1] = u1;

    // (f) s4 wave reduce -> per-wave slot
    #pragma unroll
    for (int m=1;m<64;m<<=1) s4 += __shfl_xor(s4, m, 64);
    if ((tid & 63) == 0) s_s4[tid>>6] = s4;

    // stage prefetched t+1 into the other buffer
    if (t+1 < SEQT) {
      if (tid < 64)       ((float4*)s_k[nxt])[tid]     = pf;
      else if (tid < 128) ((float4*)s_q[nxt])[tid-64]  = pf;
      else if (tid < 192) ((float4*)s_v[nxt])[tid-128] = pf;
      if (tid == 192) { s_ea[nxt][0]=pe; s_ea[nxt][1]=pa; }
    }
    __syncthreads();                                   // B2

    float s4t = s_s4[0]+s_s4[1]+s_s4[2]+s_s4[3]+s_s4[4]+s_s4[5]+s_s4[6]+s_s4[7];
    float inv = 1.0f / (sqrtf(s4t) + 1e-6f);
    float y0 = (part2[0][c0]+part2[1][c0]+part2[2][c0]+part2[3][c0]) * inv;
    float y1 = (part2[0][c1]+part2[1][c1]+part2[2][c1]+part2[3][c1]) * inv;
    if (rg == 0) { yb[t*DIMD + c0] = y0; yb[t*DIMD + c1] = y1; }
    inv_prev = inv;
  }
}

// ---------------------------------------------------------------------------
extern "C" void kernel_launch(void* const* d_in, const int* in_sizes, int n_in,
                              void* d_out, int out_size, void* d_ws, size_t ws_size,
                              hipStream_t stream)
{
  const float* x     = (const float*)d_in[0];
  const float* cosT  = (const float*)d_in[1];
  const float* sinT  = (const float*)d_in[2];
  const float* Wqkv  = (const float*)d_in[3];
  const float* qw    = (const float*)d_in[4];
  const float* qb    = (const float*)d_in[5];
  const float* kw    = (const float*)d_in[6];
  const float* kb    = (const float*)d_in[7];
  const float* vw    = (const float*)d_in[8];
  const float* vb    = (const float*)d_in[9];
  const float* Wparam= (const float*)d_in[10];
  const float* bparam= (const float*)d_in[11];
  const float* W0    = (const float*)d_in[12];
  const float* Wgate = (const float*)d_in[13];
  const float* Wout  = (const float*)d_in[14];
  float* out = (float*)d_out;

  float* ws    = (float*)d_ws;
  float* qkvr  = ws;                         // 4*1024*768  = 3,145,728 f
  float* qn    = qkvr + 4*1024*768;          // 1,048,576 f
  float* kn    = qn   + 4*1024*256;
  float* vn    = kn   + 4*1024*256;
  float* eta   = vn   + 4*1024*256;          // 4096 f
  float* alpha = eta  + 4096;                // 4096 f
  // qkvr is dead after prep_kernel -> reuse its space:
  float* yv    = qkvr;                       // scan output  (1,048,576 f)
  float* tmpg  = qkvr + 1048576;             // gate preact  (1,048,576 f)

  // 1) qkv = x @ Wqkv.T          (4096 x 768)
  gemm_bt<0><<<dim3(64*12), 256, 0, stream>>>(x, Wqkv, qkvr, 768, nullptr);
  // 2) conv + rope + l2norm + eta/alpha
  prep_kernel<<<dim3(4096), 256, 0, stream>>>(qkvr, x, cosT, sinT,
      qw, qb, kw, kb, vw, vb, Wparam, bparam, qn, kn, vn, eta, alpha);
  // 3) the sequential scan (one block per batch)
  scan_kernel<<<dim3(NB), 512, 0, stream>>>(qn, kn, vn, eta, alpha, W0, yv);
  // 4) gate preact = x @ Wgate.T (4096 x 256)
  gemm_bt<0><<<dim3(64*4), 256, 0, stream>>>(x, Wgate, tmpg, 256, nullptr);
  // 5) out = (y @ Wout.T) * sigmoid(gate)
  gemm_bt<1><<<dim3(64*4), 256, 0, stream>>>(yv, Wout, out, 256, tmpg);
}

// Round 2
// 3372.585 us; speedup vs baseline: 1.6092x; 1.6092x over previous
//
#include <hip/hip_runtime.h>

#define DIMD 256
#define SEQT 1024
#define NB   4

__device__ __forceinline__ float sigmoidf_(float x){ return 1.0f/(1.0f+expf(-x)); }

// ---------------------------------------------------------------------------
// GEMM: C[m][n] = sum_k A[m][k] * B[n][k], K = 256 fixed, tiles 64x64.
// EPI==1: C *= sigmoid(gpre[m*N+n])
// grid.x = (M/64)*(N/64)
// ---------------------------------------------------------------------------
template<int EPI>
__global__ __launch_bounds__(256) void gemm_bt(const float* __restrict__ A,
    const float* __restrict__ Bm, float* __restrict__ C, int N,
    const float* __restrict__ gpre)
{
  __shared__ float sA[64][68];
  __shared__ float sB[64][68];
  const int nb = N >> 6;
  const int bm = blockIdx.x / nb, bn = blockIdx.x - bm*nb;
  const int m0 = bm << 6, n0 = bn << 6;
  const int tid = threadIdx.x;
  const int tr = tid >> 4, tc = tid & 15;
  float acc[4][4];
  #pragma unroll
  for (int i=0;i<4;i++)
    #pragma unroll
    for (int j=0;j<4;j++) acc[i][j]=0.f;

  for (int kc=0;kc<4;kc++){
    __syncthreads();
    for (int i=tid;i<1024;i+=256){
      int r = i >> 4, q4 = i & 15;
      *(float4*)&sA[r][q4*4] = ((const float4*)(A  + (m0+r)*256 + kc*64))[q4];
      *(float4*)&sB[r][q4*4] = ((const float4*)(Bm + (n0+r)*256 + kc*64))[q4];
    }
    __syncthreads();
    #pragma unroll
    for (int kq=0;kq<16;kq++){
      float4 av[4], bv[4];
      #pragma unroll
      for (int i=0;i<4;i++) av[i] = *(const float4*)&sA[tr+16*i][kq*4];
      #pragma unroll
      for (int j=0;j<4;j++) bv[j] = *(const float4*)&sB[tc+16*j][kq*4];
      #pragma unroll
      for (int i=0;i<4;i++)
        #pragma unroll
        for (int j=0;j<4;j++)
          acc[i][j] = fmaf(av[i].x,bv[j].x, fmaf(av[i].y,bv[j].y,
                      fmaf(av[i].z,bv[j].z, fmaf(av[i].w,bv[j].w, acc[i][j]))));
    }
  }
  #pragma unroll
  for (int i=0;i<4;i++){
    #pragma unroll
    for (int j=0;j<4;j++){
      int m = m0 + tr + 16*i, n = n0 + tc + 16*j;
      float val = acc[i][j];
      if (EPI==1) val *= sigmoidf_(gpre[m*N+n]);
      C[m*N+n] = val;
    }
  }
}

// ---------------------------------------------------------------------------
// prep: causal dwconv(4) + RoPE + l2norm for q,k ; conv for v ; eta/alpha.
// one block per (b,t), 256 threads (one per d)
// ---------------------------------------------------------------------------
__global__ __launch_bounds__(256) void prep_kernel(
    const float* __restrict__ qkvr, const float* __restrict__ x,
    const float* __restrict__ cosT, const float* __restrict__ sinT,
    const float* __restrict__ qw, const float* __restrict__ qbias,
    const float* __restrict__ kw, const float* __restrict__ kbias,
    const float* __restrict__ vw, const float* __restrict__ vbias,
    const float* __restrict__ Wparam, const float* __restrict__ bparam,
    float* __restrict__ qo, float* __restrict__ ko, float* __restrict__ vo,
    float* __restrict__ eo, float* __restrict__ ao)
{
  const int bt = blockIdx.x;
  const int t = bt & 1023;
  const int d = threadIdx.x;

  float4 wq = ((const float4*)qw)[d];
  float4 wk = ((const float4*)kw)[d];
  float4 wv = ((const float4*)vw)[d];
  const float wqj[4] = {wq.x,wq.y,wq.z,wq.w};
  const float wkj[4] = {wk.x,wk.y,wk.z,wk.w};
  const float wvj[4] = {wv.x,wv.y,wv.z,wv.w};
  float qa = qbias[d], ka = kbias[d], va = vbias[d];
  #pragma unroll
  for (int j=0;j<4;j++){
    int tt = t - 3 + j;
    if (tt >= 0) {
      const float* row = qkvr + (size_t)(bt - 3 + j) * 768;
      qa = fmaf(row[d],      wqj[j], qa);
      ka = fmaf(row[256+d],  wkj[j], ka);
      va = fmaf(row[512+d],  wvj[j], va);
    }
  }
  vo[bt*256 + d] = va;

  __shared__ float sq[256], sk[256];
  __shared__ float red[4][4];
  sq[d] = qa; sk[d] = ka;
  __syncthreads();
  const int i = d >> 1;
  const float c = cosT[t*128 + i], s = sinT[t*128 + i];
  float qr, krp;
  if ((d & 1) == 0) { qr = sq[d]*c - sq[d+1]*s;  krp = sk[d]*c - sk[d+1]*s; }
  else              { qr = sq[d-1]*s + sq[d]*c;  krp = sk[d-1]*s + sk[d]*c; }

  const float xd = x[bt*256 + d];
  float r0 = qr*qr, r1 = krp*krp, r2 = xd*Wparam[d], r3 = xd*Wparam[256+d];
  #pragma unroll
  for (int m=1;m<64;m<<=1){
    r0 += __shfl_xor(r0, m, 64);
    r1 += __shfl_xor(r1, m, 64);
    r2 += __shfl_xor(r2, m, 64);
    r3 += __shfl_xor(r3, m, 64);
  }
  const int w = d >> 6;
  if ((d & 63) == 0){ red[w][0]=r0; red[w][1]=r1; red[w][2]=r2; red[w][3]=r3; }
  __syncthreads();
  float qss = red[0][0]+red[1][0]+red[2][0]+red[3][0];
  float kss = red[0][1]+red[1][1]+red[2][1]+red[3][1];
  qo[bt*256+d] = qr  / fmaxf(sqrtf(qss), 1e-12f);
  ko[bt*256+d] = krp / fmaxf(sqrtf(kss), 1e-12f);
  if (d == 0){
    float p0 = red[0][2]+red[1][2]+red[2][2]+red[3][2] + bparam[0];
    float p1 = red[0][3]+red[1][3]+red[2][3]+red[3][3] + bparam[1];
    eo[bt] = 1.f/(1.f+expf(-p0));
    ao[bt] = 1.f/(1.f+expf(-p1));
  }
}

// ---------------------------------------------------------------------------
// scan: one block per batch, 1024 threads (16 waves -> 4 waves/SIMD for
// latency hiding). Thread (rg=tid>>8, c=tid&255) owns A[rg*64..rg*64+63][c]
// in 64 registers. k is re-read from LDS (wave-broadcast, conflict-free)
// instead of a register cache so VGPRs stay <=128 (4 waves/SIMD).
// update + sumA^4 + q-dot fused into one pass over A.
// ---------------------------------------------------------------------------
__global__ __launch_bounds__(1024, 4) void scan_kernel(
    const float* __restrict__ qn, const float* __restrict__ kn,
    const float* __restrict__ vn, const float* __restrict__ eta,
    const float* __restrict__ alpha, const float* __restrict__ W0,
    float* __restrict__ y)
{
  const int b = blockIdx.x;
  const int tid = threadIdx.x;
  const int rg = tid >> 8;        // 0..3 row group
  const int c  = tid & 255;       // owned column
  const int r0 = rg << 6;         // first owned row

  __shared__ float s_k[2][256], s_q[2][256], s_v[2][256];
  __shared__ float s_ea[2][2];
  __shared__ float part[4][256], part2[4][256];
  __shared__ float s_s4[16];

  float A[64];
  #pragma unroll
  for (int j=0;j<64;j++) A[j]=0.f;

  const float* kb = kn + b*SEQT*DIMD;
  const float* qb = qn + b*SEQT*DIMD;
  const float* vb = vn + b*SEQT*DIMD;
  const float* eb = eta   + b*SEQT;
  const float* ab = alpha + b*SEQT;
  float* yb = y + b*SEQT*DIMD;

  // stage t=0 into buffer 0
  if (tid < 64)        ((float4*)s_k[0])[tid]      = ((const float4*)kb)[tid];
  else if (tid < 128)  ((float4*)s_q[0])[tid-64]   = ((const float4*)qb)[tid-64];
  else if (tid < 192)  ((float4*)s_v[0])[tid-128]  = ((const float4*)vb)[tid-128];
  if (tid == 192) { s_ea[0][0] = eb[0]; s_ea[0][1] = ab[0]; }
  __syncthreads();

  float inv_prev = 1.0f;

  for (int t=0; t<SEQT; ++t) {
    const int cur = t & 1, nxt = cur ^ 1;

    // (a) issue prefetch of step t+1 (latency hidden under compute)
    float4 pf = make_float4(0.f,0.f,0.f,0.f);
    float pe = 0.f, pa = 0.f;
    if (t+1 < SEQT) {
      if (tid < 64)       pf = ((const float4*)(kb + (t+1)*DIMD))[tid];
      else if (tid < 128) pf = ((const float4*)(qb + (t+1)*DIMD))[tid-64];
      else if (tid < 192) pf = ((const float4*)(vb + (t+1)*DIMD))[tid-128];
      if (tid == 192) { pe = eb[t+1]; pa = ab[t+1]; }
    }

    // (b) k-dot partial over owned rows
    float d0 = 0.f;
    if (t == 0) {
      // W_{-1} = W0 (A is zero): pred = k . W0
      const float* w0p = W0 + (size_t)r0*DIMD + c;
      #pragma unroll
      for (int j=0;j<64;j++)
        d0 = fmaf(s_k[0][r0+j], w0p[(size_t)j*DIMD], d0);
    } else {
      const float4* kp = (const float4*)(s_k[cur] + r0);
      #pragma unroll
      for (int jq=0;jq<16;jq++){
        float4 kv = kp[jq];
        d0 = fmaf(kv.x, A[4*jq+0], d0); d0 = fmaf(kv.y, A[4*jq+1], d0);
        d0 = fmaf(kv.z, A[4*jq+2], d0); d0 = fmaf(kv.w, A[4*jq+3], d0);
      }
      d0 *= inv_prev;   // fold W = A/denom
    }
    part[rg][c] = d0;
    __syncthreads();                                   // B1

    // (c) pred -> g (redundant across the 4 row groups, one column each)
    float pr = part[0][c]+part[1][c]+part[2][c]+part[3][c];
    const float et = s_ea[cur][0], al = s_ea[cur][1];
    float df = pr - s_v[cur][c];
    // tanh(10*diff) = 1 - 2/(exp(20*diff)+1)   (saturates correctly at +-inf)
    float e  = __expf(20.f*df);
    float th = 1.f - 2.f*__builtin_amdgcn_rcpf(e + 1.f);
    float t0 = et * 3.f * th * (df*df);

    // (d) fused: A update + sum A^4 partial + q-dot on new A
    float s4 = 0.f, u0 = 0.f;
    {
      const float4* kp = (const float4*)(s_k[cur] + r0);
      const float4* qp = (const float4*)(s_q[cur] + r0);
      #pragma unroll
      for (int jq=0;jq<16;jq++){
        float4 kv = kp[jq], qv = qp[jq];
        float a, a2;
        a = fmaf(al, A[4*jq+0], -t0*kv.x); A[4*jq+0]=a; a2=a*a; s4=fmaf(a2,a2,s4); u0=fmaf(qv.x,a,u0);
        a = fmaf(al, A[4*jq+1], -t0*kv.y); A[4*jq+1]=a; a2=a*a; s4=fmaf(a2,a2,s4); u0=fmaf(qv.y,a,u0);
        a = fmaf(al, A[4*jq+2], -t0*kv.z); A[4*jq+2]=a; a2=a*a; s4=fmaf(a2,a2,s4); u0=fmaf(qv.z,a,u0);
        a = fmaf(al, A[4*jq+3], -t0*kv.w); A[4*jq+3]=a; a2=a*a; s4=fmaf(a2,a2,s4); u0=fmaf(qv.w,a,u0);
      }
    }
    part2[rg][c] = u0;

    // (e) s4 wave reduce -> per-wave slot
    #pragma unroll
    for (int m=1;m<64;m<<=1) s4 += __shfl_xor(s4, m, 64);
    if ((tid & 63) == 0) s_s4[tid>>6] = s4;

    // stage prefetched t+1 into the other buffer
    if (t+1 < SEQT) {
      if (tid < 64)       ((float4*)s_k[nxt])[tid]     = pf;
      else if (tid < 128) ((float4*)s_q[nxt])[tid-64]  = pf;
      else if (tid < 192) ((float4*)s_v[nxt])[tid-128] = pf;
      if (tid == 192) { s_ea[nxt][0]=pe; s_ea[nxt][1]=pa; }
    }
    __syncthreads();                                   // B2

    float4 sa = ((const float4*)s_s4)[0], sb = ((const float4*)s_s4)[1];
    float4 sc = ((const float4*)s_s4)[2], sd = ((const float4*)s_s4)[3];
    float s4t = ((sa.x+sa.y)+(sa.z+sa.w)) + ((sb.x+sb.y)+(sb.z+sb.w))
              + ((sc.x+sc.y)+(sc.z+sc.w)) + ((sd.x+sd.y)+(sd.z+sd.w));
    float w   = sqrtf(s4t) + 1e-6f;
    float r   = __builtin_amdgcn_rcpf(w);
    r = r * (2.f - w*r);            // one Newton step: feeds the recurrence
    if (rg == 0)
      yb[t*DIMD + c] = (part2[0][c]+part2[1][c]+part2[2][c]+part2[3][c]) * r;
    inv_prev = r;
  }
}

// ---------------------------------------------------------------------------
extern "C" void kernel_launch(void* const* d_in, const int* in_sizes, int n_in,
                              void* d_out, int out_size, void* d_ws, size_t ws_size,
                              hipStream_t stream)
{
  const float* x     = (const float*)d_in[0];
  const float* cosT  = (const float*)d_in[1];
  const float* sinT  = (const float*)d_in[2];
  const float* Wqkv  = (const float*)d_in[3];
  const float* qw    = (const float*)d_in[4];
  const float* qb    = (const float*)d_in[5];
  const float* kw    = (const float*)d_in[6];
  const float* kb    = (const float*)d_in[7];
  const float* vw    = (const float*)d_in[8];
  const float* vb    = (const float*)d_in[9];
  const float* Wparam= (const float*)d_in[10];
  const float* bparam= (const float*)d_in[11];
  const float* W0    = (const float*)d_in[12];
  const float* Wgate = (const float*)d_in[13];
  const float* Wout  = (const float*)d_in[14];
  float* out = (float*)d_out;

  float* ws    = (float*)d_ws;
  float* qkvr  = ws;                         // 4*1024*768  = 3,145,728 f
  float* qn    = qkvr + 4*1024*768;          // 1,048,576 f
  float* kn    = qn   + 4*1024*256;
  float* vn    = kn   + 4*1024*256;
  float* eta   = vn   + 4*1024*256;          // 4096 f
  float* alpha = eta  + 4096;                // 4096 f
  // qkvr is dead after prep_kernel -> reuse its space:
  float* yv    = qkvr;                       // scan output  (1,048,576 f)
  float* tmpg  = qkvr + 1048576;             // gate preact  (1,048,576 f)

  // 1) qkv = x @ Wqkv.T          (4096 x 768)
  gemm_bt<0><<<dim3(64*12), 256, 0, stream>>>(x, Wqkv, qkvr, 768, nullptr);
  // 2) conv + rope + l2norm + eta/alpha
  prep_kernel<<<dim3(4096), 256, 0, stream>>>(qkvr, x, cosT, sinT,
      qw, qb, kw, kb, vw, vb, Wparam, bparam, qn, kn, vn, eta, alpha);
  // 3) the sequential scan (one block per batch)
  scan_kernel<<<dim3(NB), 1024, 0, stream>>>(qn, kn, vn, eta, alpha, W0, yv);
  // 4) gate preact = x @ Wgate.T (4096 x 256)
  gemm_bt<0><<<dim3(64*4), 256, 0, stream>>>(x, Wgate, tmpg, 256, nullptr);
  // 5) out = (y @ Wout.T) * sigmoid(gate)
  gemm_bt<1><<<dim3(64*4), 256, 0, stream>>>(yv, Wout, out, 256, tmpg);
}

// Round 3
// 3090.991 us; speedup vs baseline: 1.7558x; 1.0911x over previous
//
#include <hip/hip_runtime.h>

#define DIMD 256
#define SEQT 1024
#define NB   4

typedef float v2f __attribute__((ext_vector_type(2)));
#define FMA2(a,b,c) __builtin_elementwise_fma((a),(b),(c))

__device__ __forceinline__ float sigmoidf_(float x){ return 1.0f/(1.0f+expf(-x)); }

// ---------------------------------------------------------------------------
// GEMM: C[m][n] = sum_k A[m][k] * B[n][k], K = 256 fixed, tiles 64x64.
// EPI==1: C *= sigmoid(gpre[m*N+n])
// grid.x = (M/64)*(N/64)
// ---------------------------------------------------------------------------
template<int EPI>
__global__ __launch_bounds__(256) void gemm_bt(const float* __restrict__ A,
    const float* __restrict__ Bm, float* __restrict__ C, int N,
    const float* __restrict__ gpre)
{
  __shared__ float sA[64][68];
  __shared__ float sB[64][68];
  const int nb = N >> 6;
  const int bm = blockIdx.x / nb, bn = blockIdx.x - bm*nb;
  const int m0 = bm << 6, n0 = bn << 6;
  const int tid = threadIdx.x;
  const int tr = tid >> 4, tc = tid & 15;
  float acc[4][4];
  #pragma unroll
  for (int i=0;i<4;i++)
    #pragma unroll
    for (int j=0;j<4;j++) acc[i][j]=0.f;

  for (int kc=0;kc<4;kc++){
    __syncthreads();
    for (int i=tid;i<1024;i+=256){
      int r = i >> 4, q4 = i & 15;
      *(float4*)&sA[r][q4*4] = ((const float4*)(A  + (m0+r)*256 + kc*64))[q4];
      *(float4*)&sB[r][q4*4] = ((const float4*)(Bm + (n0+r)*256 + kc*64))[q4];
    }
    __syncthreads();
    #pragma unroll
    for (int kq=0;kq<16;kq++){
      float4 av[4], bv[4];
      #pragma unroll
      for (int i=0;i<4;i++) av[i] = *(const float4*)&sA[tr+16*i][kq*4];
      #pragma unroll
      for (int j=0;j<4;j++) bv[j] = *(const float4*)&sB[tc+16*j][kq*4];
      #pragma unroll
      for (int i=0;i<4;i++)
        #pragma unroll
        for (int j=0;j<4;j++)
          acc[i][j] = fmaf(av[i].x,bv[j].x, fmaf(av[i].y,bv[j].y,
                      fmaf(av[i].z,bv[j].z, fmaf(av[i].w,bv[j].w, acc[i][j]))));
    }
  }
  #pragma unroll
  for (int i=0;i<4;i++){
    #pragma unroll
    for (int j=0;j<4;j++){
      int m = m0 + tr + 16*i, n = n0 + tc + 16*j;
      float val = acc[i][j];
      if (EPI==1) val *= sigmoidf_(gpre[m*N+n]);
      C[m*N+n] = val;
    }
  }
}

// ---------------------------------------------------------------------------
// prep: causal dwconv(4) + RoPE + l2norm for q,k ; conv for v ; eta/alpha.
// one block per (b,t), 256 threads (one per d)
// ---------------------------------------------------------------------------
__global__ __launch_bounds__(256) void prep_kernel(
    const float* __restrict__ qkvr, const float* __restrict__ x,
    const float* __restrict__ cosT, const float* __restrict__ sinT,
    const float* __restrict__ qw, const float* __restrict__ qbias,
    const float* __restrict__ kw, const float* __restrict__ kbias,
    const float* __restrict__ vw, const float* __restrict__ vbias,
    const float* __restrict__ Wparam, const float* __restrict__ bparam,
    float* __restrict__ qo, float* __restrict__ ko, float* __restrict__ vo,
    float* __restrict__ eo, float* __restrict__ ao)
{
  const int bt = blockIdx.x;
  const int t = bt & 1023;
  const int d = threadIdx.x;

  float4 wq = ((const float4*)qw)[d];
  float4 wk = ((const float4*)kw)[d];
  float4 wv = ((const float4*)vw)[d];
  const float wqj[4] = {wq.x,wq.y,wq.z,wq.w};
  const float wkj[4] = {wk.x,wk.y,wk.z,wk.w};
  const float wvj[4] = {wv.x,wv.y,wv.z,wv.w};
  float qa = qbias[d], ka = kbias[d], va = vbias[d];
  #pragma unroll
  for (int j=0;j<4;j++){
    int tt = t - 3 + j;
    if (tt >= 0) {
      const float* row = qkvr + (size_t)(bt - 3 + j) * 768;
      qa = fmaf(row[d],      wqj[j], qa);
      ka = fmaf(row[256+d],  wkj[j], ka);
      va = fmaf(row[512+d],  wvj[j], va);
    }
  }
  vo[bt*256 + d] = va;

  __shared__ float sq[256], sk[256];
  __shared__ float red[4][4];
  sq[d] = qa; sk[d] = ka;
  __syncthreads();
  const int i = d >> 1;
  const float c = cosT[t*128 + i], s = sinT[t*128 + i];
  float qr, krp;
  if ((d & 1) == 0) { qr = sq[d]*c - sq[d+1]*s;  krp = sk[d]*c - sk[d+1]*s; }
  else              { qr = sq[d-1]*s + sq[d]*c;  krp = sk[d-1]*s + sk[d]*c; }

  const float xd = x[bt*256 + d];
  float r0 = qr*qr, r1 = krp*krp, r2 = xd*Wparam[d], r3 = xd*Wparam[256+d];
  #pragma unroll
  for (int m=1;m<64;m<<=1){
    r0 += __shfl_xor(r0, m, 64);
    r1 += __shfl_xor(r1, m, 64);
    r2 += __shfl_xor(r2, m, 64);
    r3 += __shfl_xor(r3, m, 64);
  }
  const int w = d >> 6;
  if ((d & 63) == 0){ red[w][0]=r0; red[w][1]=r1; red[w][2]=r2; red[w][3]=r3; }
  __syncthreads();
  float qss = red[0][0]+red[1][0]+red[2][0]+red[3][0];
  float kss = red[0][1]+red[1][1]+red[2][1]+red[3][1];
  qo[bt*256+d] = qr  / fmaxf(sqrtf(qss), 1e-12f);
  ko[bt*256+d] = krp / fmaxf(sqrtf(kss), 1e-12f);
  if (d == 0){
    float p0 = red[0][2]+red[1][2]+red[2][2]+red[3][2] + bparam[0];
    float p1 = red[0][3]+red[1][3]+red[2][3]+red[3][3] + bparam[1];
    eo[bt] = 1.f/(1.f+expf(-p0));
    ao[bt] = 1.f/(1.f+expf(-p1));
  }
}

// ---------------------------------------------------------------------------
// scan: one block per batch, 1024 threads (16 waves -> 4 waves/SIMD).
// Thread (rg=tid>>8, c=tid&255) owns A[rg*64..rg*64+63][c] as 32 float2
// registers. Hot loops use float2 ext-vector math so the compiler emits
// v_pk_fma_f32 / v_pk_mul_f32 (2 fp32 ops per issue slot on gfx950).
// Accumulators are split so no dependent pk-FMA chain exceeds 16.
// ---------------------------------------------------------------------------
__global__ __launch_bounds__(1024, 4) void scan_kernel(
    const float* __restrict__ qn, const float* __restrict__ kn,
    const float* __restrict__ vn, const float* __restrict__ eta,
    const float* __restrict__ alpha, const float* __restrict__ W0,
    float* __restrict__ y)
{
  const int b = blockIdx.x;
  const int tid = threadIdx.x;
  const int rg = tid >> 8;        // 0..3 row group
  const int c  = tid & 255;       // owned column
  const int r0 = rg << 6;         // first owned row

  __shared__ float s_k[2][256], s_q[2][256], s_v[2][256];
  __shared__ float s_ea[2][2];
  __shared__ float part[4][256], part2[4][256];
  __shared__ float s_s4[16];

  v2f A2[32];
  #pragma unroll
  for (int j=0;j<32;j++) A2[j] = (v2f)(0.f);

  const float* kb = kn + b*SEQT*DIMD;
  const float* qb = qn + b*SEQT*DIMD;
  const float* vb = vn + b*SEQT*DIMD;
  const float* eb = eta   + b*SEQT;
  const float* ab = alpha + b*SEQT;
  float* yb = y + b*SEQT*DIMD;

  // stage t=0 into buffer 0
  if (tid < 64)        ((float4*)s_k[0])[tid]      = ((const float4*)kb)[tid];
  else if (tid < 128)  ((float4*)s_q[0])[tid-64]   = ((const float4*)qb)[tid-64];
  else if (tid < 192)  ((float4*)s_v[0])[tid-128]  = ((const float4*)vb)[tid-128];
  if (tid == 192) { s_ea[0][0] = eb[0]; s_ea[0][1] = ab[0]; }
  __syncthreads();

  float inv_prev = 1.0f;

  for (int t=0; t<SEQT; ++t) {
    const int cur = t & 1, nxt = cur ^ 1;

    // (a) issue prefetch of step t+1 (latency hidden under compute)
    float4 pf = make_float4(0.f,0.f,0.f,0.f);
    float pe = 0.f, pa = 0.f;
    if (t+1 < SEQT) {
      if (tid < 64)       pf = ((const float4*)(kb + (t+1)*DIMD))[tid];
      else if (tid < 128) pf = ((const float4*)(qb + (t+1)*DIMD))[tid-64];
      else if (tid < 192) pf = ((const float4*)(vb + (t+1)*DIMD))[tid-128];
      if (tid == 192) { pe = eb[t+1]; pa = ab[t+1]; }
    }

    // (b) k-dot partial over owned rows (packed, 2 accumulators)
    float d0;
    if (t == 0) {
      // W_{-1} = W0 (A is zero): pred = k . W0
      const float* w0p = W0 + (size_t)r0*DIMD + c;
      float acc = 0.f;
      #pragma unroll
      for (int j=0;j<64;j++)
        acc = fmaf(s_k[0][r0+j], w0p[(size_t)j*DIMD], acc);
      d0 = acc;
    } else {
      const float4* kp = (const float4*)(s_k[cur] + r0);
      v2f acc0 = (v2f)(0.f), acc1 = (v2f)(0.f);
      #pragma unroll
      for (int jq=0;jq<16;jq++){
        float4 kv = kp[jq];
        v2f klo = {kv.x, kv.y}, khi = {kv.z, kv.w};
        acc0 = FMA2(klo, A2[2*jq],   acc0);
        acc1 = FMA2(khi, A2[2*jq+1], acc1);
      }
      d0 = ((acc0.x + acc0.y) + (acc1.x + acc1.y)) * inv_prev;  // fold W=A/denom
    }
    part[rg][c] = d0;
    __syncthreads();                                   // B1

    // (c) pred -> g (redundant across the 4 row groups, one column each)
    float pr = part[0][c]+part[1][c]+part[2][c]+part[3][c];
    const float et = s_ea[cur][0], al = s_ea[cur][1];
    float df = pr - s_v[cur][c];
    // tanh(10*diff) = 1 - 2/(exp(20*diff)+1)   (saturates correctly at +-inf)
    float e  = __expf(20.f*df);
    float th = 1.f - 2.f*__builtin_amdgcn_rcpf(e + 1.f);
    float t0 = et * 3.f * th * (df*df);

    // (d) fused: A update + sum A^4 partial + q-dot on new A (packed)
    const v2f alv = {al, al};
    const v2f nt0 = {-t0, -t0};
    v2f s4a = (v2f)(0.f), s4b = (v2f)(0.f);
    v2f u2a = (v2f)(0.f), u2b = (v2f)(0.f);
    {
      const float4* kp = (const float4*)(s_k[cur] + r0);
      const float4* qp = (const float4*)(s_q[cur] + r0);
      #pragma unroll
      for (int jq=0;jq<16;jq++){
        float4 kv = kp[jq], qv = qp[jq];
        v2f klo = {kv.x, kv.y}, khi = {kv.z, kv.w};
        v2f qlo = {qv.x, qv.y}, qhi = {qv.z, qv.w};
        v2f a, a2;
        a = FMA2(alv, A2[2*jq],   nt0*klo); A2[2*jq]   = a;
        a2 = a*a; s4a = FMA2(a2, a2, s4a);  u2a = FMA2(qlo, a, u2a);
        a = FMA2(alv, A2[2*jq+1], nt0*khi); A2[2*jq+1] = a;
        a2 = a*a; s4b = FMA2(a2, a2, s4b);  u2b = FMA2(qhi, a, u2b);
      }
    }
    part2[rg][c] = (u2a.x + u2a.y) + (u2b.x + u2b.y);
    float s4 = (s4a.x + s4a.y) + (s4b.x + s4b.y);

    // (e) s4 wave reduce -> per-wave slot
    #pragma unroll
    for (int m=1;m<64;m<<=1) s4 += __shfl_xor(s4, m, 64);
    if ((tid & 63) == 0) s_s4[tid>>6] = s4;

    // stage prefetched t+1 into the other buffer
    if (t+1 < SEQT) {
      if (tid < 64)       ((float4*)s_k[nxt])[tid]     = pf;
      else if (tid < 128) ((float4*)s_q[nxt])[tid-64]  = pf;
      else if (tid < 192) ((float4*)s_v[nxt])[tid-128] = pf;
      if (tid == 192) { s_ea[nxt][0]=pe; s_ea[nxt][1]=pa; }
    }
    __syncthreads();                                   // B2

    float4 sa = ((const float4*)s_s4)[0], sb = ((const float4*)s_s4)[1];
    float4 sc = ((const float4*)s_s4)[2], sd = ((const float4*)s_s4)[3];
    float s4t = ((sa.x+sa.y)+(sa.z+sa.w)) + ((sb.x+sb.y)+(sb.z+sb.w))
              + ((sc.x+sc.y)+(sc.z+sc.w)) + ((sd.x+sd.y)+(sd.z+sd.w));
    float w   = sqrtf(s4t) + 1e-6f;
    float r   = __builtin_amdgcn_rcpf(w);
    r = r * (2.f - w*r);            // one Newton step: feeds the recurrence
    if (rg == 0)
      yb[t*DIMD + c] = (part2[0][c]+part2[1][c]+part2[2][c]+part2[3][c]) * r;
    inv_prev = r;
  }
}

// ---------------------------------------------------------------------------
extern "C" void kernel_launch(void* const* d_in, const int* in_sizes, int n_in,
                              void* d_out, int out_size, void* d_ws, size_t ws_size,
                              hipStream_t stream)
{
  const float* x     = (const float*)d_in[0];
  const float* cosT  = (const float*)d_in[1];
  const float* sinT  = (const float*)d_in[2];
  const float* Wqkv  = (const float*)d_in[3];
  const float* qw    = (const float*)d_in[4];
  const float* qb    = (const float*)d_in[5];
  const float* kw    = (const float*)d_in[6];
  const float* kb    = (const float*)d_in[7];
  const float* vw    = (const float*)d_in[8];
  const float* vb    = (const float*)d_in[9];
  const float* Wparam= (const float*)d_in[10];
  const float* bparam= (const float*)d_in[11];
  const float* W0    = (const float*)d_in[12];
  const float* Wgate = (const float*)d_in[13];
  const float* Wout  = (const float*)d_in[14];
  float* out = (float*)d_out;

  float* ws    = (float*)d_ws;
  float* qkvr  = ws;                         // 4*1024*768  = 3,145,728 f
  float* qn    = qkvr + 4*1024*768;          // 1,048,576 f
  float* kn    = qn   + 4*1024*256;
  float* vn    = kn   + 4*1024*256;
  float* eta   = vn   + 4*1024*256;          // 4096 f
  float* alpha = eta  + 4096;                // 4096 f
  // qkvr is dead after prep_kernel -> reuse its space:
  float* yv    = qkvr;                       // scan output  (1,048,576 f)
  float* tmpg  = qkvr + 1048576;             // gate preact  (1,048,576 f)

  // 1) qkv = x @ Wqkv.T          (4096 x 768)
  gemm_bt<0><<<dim3(64*12), 256, 0, stream>>>(x, Wqkv, qkvr, 768, nullptr);
  // 2) conv + rope + l2norm + eta/alpha
  prep_kernel<<<dim3(4096), 256, 0, stream>>>(qkvr, x, cosT, sinT,
      qw, qb, kw, kb, vw, vb, Wparam, bparam, qn, kn, vn, eta, alpha);
  // 3) the sequential scan (one block per batch)
  scan_kernel<<<dim3(NB), 1024, 0, stream>>>(qn, kn, vn, eta, alpha, W0, yv);
  // 4) gate preact = x @ Wgate.T (4096 x 256)
  gemm_bt<0><<<dim3(64*4), 256, 0, stream>>>(x, Wgate, tmpg, 256, nullptr);
  // 5) out = (y @ Wout.T) * sigmoid(gate)
  gemm_bt<1><<<dim3(64*4), 256, 0, stream>>>(yv, Wout, out, 256, tmpg);
}

// Round 4
// 3050.975 us; speedup vs baseline: 1.7788x; 1.0131x over previous
//
#include <hip/hip_runtime.h>

#define DIMD 256
#define SEQT 1024
#define NB   4
#define KSTRIDE 272   // 256 + 4-float stagger pad per 64-row block

typedef float v2f __attribute__((ext_vector_type(2)));
#define FMA2(a,b,c) __builtin_elementwise_fma((a),(b),(c))

__device__ __forceinline__ float sigmoidf_(float x){ return 1.0f/(1.0f+expf(-x)); }

// ---------------------------------------------------------------------------
// GEMM: C[m][n] = sum_k A[m][k] * B[n][k], K = 256 fixed, tiles 64x64.
// EPI==1: C *= sigmoid(gpre[m*N+n])
// ---------------------------------------------------------------------------
template<int EPI>
__global__ __launch_bounds__(256) void gemm_bt(const float* __restrict__ A,
    const float* __restrict__ Bm, float* __restrict__ C, int N,
    const float* __restrict__ gpre)
{
  __shared__ float sA[64][68];
  __shared__ float sB[64][68];
  const int nb = N >> 6;
  const int bm = blockIdx.x / nb, bn = blockIdx.x - bm*nb;
  const int m0 = bm << 6, n0 = bn << 6;
  const int tid = threadIdx.x;
  const int tr = tid >> 4, tc = tid & 15;
  float acc[4][4];
  #pragma unroll
  for (int i=0;i<4;i++)
    #pragma unroll
    for (int j=0;j<4;j++) acc[i][j]=0.f;

  for (int kc=0;kc<4;kc++){
    __syncthreads();
    for (int i=tid;i<1024;i+=256){
      int r = i >> 4, q4 = i & 15;
      *(float4*)&sA[r][q4*4] = ((const float4*)(A  + (m0+r)*256 + kc*64))[q4];
      *(float4*)&sB[r][q4*4] = ((const float4*)(Bm + (n0+r)*256 + kc*64))[q4];
    }
    __syncthreads();
    #pragma unroll
    for (int kq=0;kq<16;kq++){
      float4 av[4], bv[4];
      #pragma unroll
      for (int i=0;i<4;i++) av[i] = *(const float4*)&sA[tr+16*i][kq*4];
      #pragma unroll
      for (int j=0;j<4;j++) bv[j] = *(const float4*)&sB[tc+16*j][kq*4];
      #pragma unroll
      for (int i=0;i<4;i++)
        #pragma unroll
        for (int j=0;j<4;j++)
          acc[i][j] = fmaf(av[i].x,bv[j].x, fmaf(av[i].y,bv[j].y,
                      fmaf(av[i].z,bv[j].z, fmaf(av[i].w,bv[j].w, acc[i][j]))));
    }
  }
  #pragma unroll
  for (int i=0;i<4;i++){
    #pragma unroll
    for (int j=0;j<4;j++){
      int m = m0 + tr + 16*i, n = n0 + tc + 16*j;
      float val = acc[i][j];
      if (EPI==1) val *= sigmoidf_(gpre[m*N+n]);
      C[m*N+n] = val;
    }
  }
}

// ---------------------------------------------------------------------------
// prep: causal dwconv(4) + RoPE + l2norm for q,k ; conv for v ; eta/alpha.
// ---------------------------------------------------------------------------
__global__ __launch_bounds__(256) void prep_kernel(
    const float* __restrict__ qkvr, const float* __restrict__ x,
    const float* __restrict__ cosT, const float* __restrict__ sinT,
    const float* __restrict__ qw, const float* __restrict__ qbias,
    const float* __restrict__ kw, const float* __restrict__ kbias,
    const float* __restrict__ vw, const float* __restrict__ vbias,
    const float* __restrict__ Wparam, const float* __restrict__ bparam,
    float* __restrict__ qo, float* __restrict__ ko, float* __restrict__ vo,
    float* __restrict__ eo, float* __restrict__ ao)
{
  const int bt = blockIdx.x;
  const int t = bt & 1023;
  const int d = threadIdx.x;

  float4 wq = ((const float4*)qw)[d];
  float4 wk = ((const float4*)kw)[d];
  float4 wv = ((const float4*)vw)[d];
  const float wqj[4] = {wq.x,wq.y,wq.z,wq.w};
  const float wkj[4] = {wk.x,wk.y,wk.z,wk.w};
  const float wvj[4] = {wv.x,wv.y,wv.z,wv.w};
  float qa = qbias[d], ka = kbias[d], va = vbias[d];
  #pragma unroll
  for (int j=0;j<4;j++){
    int tt = t - 3 + j;
    if (tt >= 0) {
      const float* row = qkvr + (size_t)(bt - 3 + j) * 768;
      qa = fmaf(row[d],      wqj[j], qa);
      ka = fmaf(row[256+d],  wkj[j], ka);
      va = fmaf(row[512+d],  wvj[j], va);
    }
  }
  vo[bt*256 + d] = va;

  __shared__ float sq[256], sk[256];
  __shared__ float red[4][4];
  sq[d] = qa; sk[d] = ka;
  __syncthreads();
  const int i = d >> 1;
  const float c = cosT[t*128 + i], s = sinT[t*128 + i];
  float qr, krp;
  if ((d & 1) == 0) { qr = sq[d]*c - sq[d+1]*s;  krp = sk[d]*c - sk[d+1]*s; }
  else              { qr = sq[d-1]*s + sq[d]*c;  krp = sk[d-1]*s + sk[d]*c; }

  const float xd = x[bt*256 + d];
  float r0 = qr*qr, r1 = krp*krp, r2 = xd*Wparam[d], r3 = xd*Wparam[256+d];
  #pragma unroll
  for (int m=1;m<64;m<<=1){
    r0 += __shfl_xor(r0, m, 64);
    r1 += __shfl_xor(r1, m, 64);
    r2 += __shfl_xor(r2, m, 64);
    r3 += __shfl_xor(r3, m, 64);
  }
  const int w = d >> 6;
  if ((d & 63) == 0){ red[w][0]=r0; red[w][1]=r1; red[w][2]=r2; red[w][3]=r3; }
  __syncthreads();
  float qss = red[0][0]+red[1][0]+red[2][0]+red[3][0];
  float kss = red[0][1]+red[1][1]+red[2][1]+red[3][1];
  qo[bt*256+d] = qr  / fmaxf(sqrtf(qss), 1e-12f);
  ko[bt*256+d] = krp / fmaxf(sqrtf(kss), 1e-12f);
  if (d == 0){
    float p0 = red[0][2]+red[1][2]+red[2][2]+red[3][2] + bparam[0];
    float p1 = red[0][3]+red[1][3]+red[2][3]+red[3][3] + bparam[1];
    eo[bt] = 1.f/(1.f+expf(-p0));
    ao[bt] = 1.f/(1.f+expf(-p1));
  }
}

// ---------------------------------------------------------------------------
// scan: one block per batch, 1024 threads, ONE barrier per step.
// Thread (c=tid>>2, rg=tid&3) owns A[rg*64..rg*64+63][c] as 32 v2f regs.
// The 4 row-group partials of a column live in adjacent lanes -> pred and
// q-dot reduce via 2x __shfl_xor (no LDS, no barrier). Only the scalar
// sumA^4 crosses waves; it is consumed one step later, so a single barrier
// per step suffices. k/q/v/ea triple-buffered (write pre(t) to buf (t+1)%3,
// last read post(t+1): always barrier-separated); s_s4 double-buffered.
// k/q stored with a 4-float stagger per 64-row block (stride 68) so the
// 4 per-rg b128 read streams are bank-conflict-free.
// ---------------------------------------------------------------------------
__global__ __launch_bounds__(1024, 4) void scan_kernel(
    const float* __restrict__ qn, const float* __restrict__ kn,
    const float* __restrict__ vn, const float* __restrict__ eta,
    const float* __restrict__ alpha, const float* __restrict__ W0,
    float* __restrict__ y)
{
  const int b = blockIdx.x;
  const int tid = threadIdx.x;
  const int rg = tid & 3;         // row group
  const int c  = tid >> 2;        // owned column
  const int r0 = rg << 6;         // first owned row
  const int koff = 68 * rg;       // staggered base of this row block

  __shared__ float s_k[3][KSTRIDE], s_q[3][KSTRIDE], s_v[3][256];
  __shared__ float s_ea[3][2];
  __shared__ float s_s4[2][16];

  v2f A2[32];
  #pragma unroll
  for (int j=0;j<32;j++) A2[j] = (v2f)(0.f);

  const float* kb = kn + b*SEQT*DIMD;
  const float* qb = qn + b*SEQT*DIMD;
  const float* vb = vn + b*SEQT*DIMD;
  const float* eb = eta   + b*SEQT;
  const float* ab = alpha + b*SEQT;
  float* yb = y + b*SEQT*DIMD;

  // prologue: stage t=0 into buf0 ; load t=1 into pf regs
  if (tid < 64) {
    float4 v0 = ((const float4*)kb)[tid];
    *(float4*)&s_k[0][4*tid + (tid>>4)*4] = v0;
  } else if (tid < 128) {
    int i = tid-64;
    float4 v0 = ((const float4*)qb)[i];
    *(float4*)&s_q[0][4*i + (i>>4)*4] = v0;
  } else if (tid < 192) {
    ((float4*)s_v[0])[tid-128] = ((const float4*)vb)[tid-128];
  }
  if (tid == 192) { s_ea[0][0] = eb[0]; s_ea[0][1] = ab[0]; }

  float4 pf = make_float4(0.f,0.f,0.f,0.f);
  float pe = 0.f, pa = 0.f;
  if (tid < 64)       pf = ((const float4*)(kb + DIMD))[tid];
  else if (tid < 128) pf = ((const float4*)(qb + DIMD))[tid-64];
  else if (tid < 192) pf = ((const float4*)(vb + DIMD))[tid-128];
  if (tid == 192) { pe = eb[1]; pa = ab[1]; }
  __syncthreads();

  float inv_prev = 1.0f;
  float u_prev = 0.f;
  int cur = 0;

  for (int t=0; t<SEQT; ++t) {
    const int nxt = (cur==2) ? 0 : cur+1;

    // ---- pre-phase: stage pf (t+1 data, loaded last post-phase) -> buf nxt
    if (t+1 < SEQT) {
      if (tid < 64)       *(float4*)&s_k[nxt][4*tid + (tid>>4)*4] = pf;
      else if (tid < 128){ int i = tid-64; *(float4*)&s_q[nxt][4*i + (i>>4)*4] = pf; }
      else if (tid < 192) ((float4*)s_v[nxt])[tid-128] = pf;
      if (tid == 192) { s_ea[nxt][0]=pe; s_ea[nxt][1]=pa; }
    }

    // ---- k-dot partial over owned rows (packed)
    float pred_raw;
    if (t == 0) {
      const float* w0p = W0 + (size_t)r0*DIMD + c;
      const float* kq = s_k[0] + koff;
      float acc = 0.f;
      #pragma unroll
      for (int j=0;j<64;j++)
        acc = fmaf(kq[j], w0p[(size_t)j*DIMD], acc);
      pred_raw = acc;
    } else {
      const float4* kp = (const float4*)(s_k[cur] + koff);
      v2f acc0 = (v2f)(0.f), acc1 = (v2f)(0.f);
      #pragma unroll
      for (int jq=0;jq<16;jq++){
        float4 kv = kp[jq];
        v2f klo = {kv.x, kv.y}, khi = {kv.z, kv.w};
        acc0 = FMA2(klo, A2[2*jq],   acc0);
        acc1 = FMA2(khi, A2[2*jq+1], acc1);
      }
      pred_raw = (acc0.x + acc0.y) + (acc1.x + acc1.y);
    }
    // in-wave cross-rg reduce (lanes ^1, ^2 share the column)
    pred_raw += __shfl_xor(pred_raw, 1, 64);
    pred_raw += __shfl_xor(pred_raw, 2, 64);

    __syncthreads();                                   // the ONE barrier

    // ---- post-phase
    // issue prefetch for t+2 (lands during fused loop; staged next pre-phase)
    if (t+2 < SEQT) {
      if (tid < 64)       pf = ((const float4*)(kb + (t+2)*DIMD))[tid];
      else if (tid < 128) pf = ((const float4*)(qb + (t+2)*DIMD))[tid-64];
      else if (tid < 192) pf = ((const float4*)(vb + (t+2)*DIMD))[tid-128];
      if (tid == 192) { pe = eb[t+2]; pa = ab[t+2]; }
    }

    // inv from previous step's sumA^4 ; deferred y-write for t-1
    if (t > 0) {
      const float* sp = s_s4[(t-1)&1];
      float4 sa = ((const float4*)sp)[0], sb4 = ((const float4*)sp)[1];
      float4 sc4= ((const float4*)sp)[2], sd4 = ((const float4*)sp)[3];
      float s4t = ((sa.x+sa.y)+(sa.z+sa.w)) + ((sb4.x+sb4.y)+(sb4.z+sb4.w))
                + ((sc4.x+sc4.y)+(sc4.z+sc4.w)) + ((sd4.x+sd4.y)+(sd4.z+sd4.w));
      float w = sqrtf(s4t) + 1e-6f;
      float r = __builtin_amdgcn_rcpf(w);
      r = r * (2.f - w*r);          // Newton: feeds the recurrence
      inv_prev = r;
      if (rg == 0) yb[(t-1)*DIMD + c] = u_prev * r;
    }

    float pred = pred_raw * inv_prev;
    const float et = s_ea[cur][0], al = s_ea[cur][1];
    float df = pred - s_v[cur][c];
    // tanh(10*df) = 1 - 2/(exp(20*df)+1)
    float e  = __expf(20.f*df);
    float th = 1.f - 2.f*__builtin_amdgcn_rcpf(e + 1.f);
    float t0 = et * 3.f * th * (df*df);

    // fused: A update + sumA^4 partial + q-dot on new A (packed)
    const v2f alv = {al, al};
    const v2f nt0 = {-t0, -t0};
    v2f s4a = (v2f)(0.f), s4b = (v2f)(0.f);
    v2f u2a = (v2f)(0.f), u2b = (v2f)(0.f);
    {
      const float4* kp = (const float4*)(s_k[cur] + koff);
      const float4* qp = (const float4*)(s_q[cur] + koff);
      #pragma unroll
      for (int jq=0;jq<16;jq++){
        float4 kv = kp[jq], qv = qp[jq];
        v2f klo = {kv.x, kv.y}, khi = {kv.z, kv.w};
        v2f qlo = {qv.x, qv.y}, qhi = {qv.z, qv.w};
        v2f a, a2;
        a = FMA2(alv, A2[2*jq],   nt0*klo); A2[2*jq]   = a;
        a2 = a*a; s4a = FMA2(a2, a2, s4a);  u2a = FMA2(qlo, a, u2a);
        a = FMA2(alv, A2[2*jq+1], nt0*khi); A2[2*jq+1] = a;
        a2 = a*a; s4b = FMA2(a2, a2, s4b);  u2b = FMA2(qhi, a, u2b);
      }
    }
    float u = (u2a.x + u2a.y) + (u2b.x + u2b.y);
    u += __shfl_xor(u, 1, 64);
    u += __shfl_xor(u, 2, 64);
    u_prev = u;

    float s4 = (s4a.x + s4a.y) + (s4b.x + s4b.y);
    #pragma unroll
    for (int m=1;m<64;m<<=1) s4 += __shfl_xor(s4, m, 64);
    if ((tid & 63) == 0) s_s4[t&1][tid>>6] = s4;

    cur = nxt;
  }

  __syncthreads();
  // epilogue: y for t = 1023 (s4 sits in s_s4[1023&1 = 1])
  {
    const float* sp = s_s4[1];
    float4 sa = ((const float4*)sp)[0], sb4 = ((const float4*)sp)[1];
    float4 sc4= ((const float4*)sp)[2], sd4 = ((const float4*)sp)[3];
    float s4t = ((sa.x+sa.y)+(sa.z+sa.w)) + ((sb4.x+sb4.y)+(sb4.z+sb4.w))
              + ((sc4.x+sc4.y)+(sc4.z+sc4.w)) + ((sd4.x+sd4.y)+(sd4.z+sd4.w));
    float w = sqrtf(s4t) + 1e-6f;
    float r = __builtin_amdgcn_rcpf(w);
    r = r * (2.f - w*r);
    if (rg == 0) yb[1023*DIMD + c] = u_prev * r;
  }
}

// ---------------------------------------------------------------------------
extern "C" void kernel_launch(void* const* d_in, const int* in_sizes, int n_in,
                              void* d_out, int out_size, void* d_ws, size_t ws_size,
                              hipStream_t stream)
{
  const float* x     = (const float*)d_in[0];
  const float* cosT  = (const float*)d_in[1];
  const float* sinT  = (const float*)d_in[2];
  const float* Wqkv  = (const float*)d_in[3];
  const float* qw    = (const float*)d_in[4];
  const float* qb    = (const float*)d_in[5];
  const float* kw    = (const float*)d_in[6];
  const float* kb    = (const float*)d_in[7];
  const float* vw    = (const float*)d_in[8];
  const float* vb    = (const float*)d_in[9];
  const float* Wparam= (const float*)d_in[10];
  const float* bparam= (const float*)d_in[11];
  const float* W0    = (const float*)d_in[12];
  const float* Wgate = (const float*)d_in[13];
  const float* Wout  = (const float*)d_in[14];
  float* out = (float*)d_out;

  float* ws    = (float*)d_ws;
  float* qkvr  = ws;                         // 4*1024*768  = 3,145,728 f
  float* qn    = qkvr + 4*1024*768;          // 1,048,576 f
  float* kn    = qn   + 4*1024*256;
  float* vn    = kn   + 4*1024*256;
  float* eta   = vn   + 4*1024*256;          // 4096 f
  float* alpha = eta  + 4096;                // 4096 f
  // qkvr is dead after prep_kernel -> reuse its space:
  float* yv    = qkvr;                       // scan output  (1,048,576 f)
  float* tmpg  = qkvr + 1048576;             // gate preact  (1,048,576 f)

  // 1) qkv = x @ Wqkv.T          (4096 x 768)
  gemm_bt<0><<<dim3(64*12), 256, 0, stream>>>(x, Wqkv, qkvr, 768, nullptr);
  // 2) conv + rope + l2norm + eta/alpha
  prep_kernel<<<dim3(4096), 256, 0, stream>>>(qkvr, x, cosT, sinT,
      qw, qb, kw, kb, vw, vb, Wparam, bparam, qn, kn, vn, eta, alpha);
  // 3) the sequential scan (one block per batch)
  scan_kernel<<<dim3(NB), 1024, 0, stream>>>(qn, kn, vn, eta, alpha, W0, yv);
  // 4) gate preact = x @ Wgate.T (4096 x 256)
  gemm_bt<0><<<dim3(64*4), 256, 0, stream>>>(x, Wgate, tmpg, 256, nullptr);
  // 5) out = (y @ Wout.T) * sigmoid(gate)
  gemm_bt<1><<<dim3(64*4), 256, 0, stream>>>(yv, Wout, out, 256, tmpg);
}